// Round 4
// baseline (8290.869 us; speedup 1.0000x reference)
//
#include <hip/hip_runtime.h>
#include <hip/hip_fp16.h>

#define BB 32
#define LL 512
#define HH 1024
#define NL 4
#define RS 8     // h ring slots per layer
#define TPL 32   // blocks (tiles) per layer
#define CPB 32   // output cols per block

typedef _Float16 f16x8 __attribute__((ext_vector_type(8)));
typedef _Float16 f16x4 __attribute__((ext_vector_type(4)));
typedef float    f32x4 __attribute__((ext_vector_type(4)));

__device__ __forceinline__ f16x8 cvt8(const float* __restrict__ p) {
  f32x4 lo = *reinterpret_cast<const f32x4*>(p);
  f32x4 hi = *reinterpret_cast<const f32x4*>(p + 4);
  f16x8 r;
#pragma unroll
  for (int e = 0; e < 4; ++e) { r[e] = (_Float16)lo[e]; r[e + 4] = (_Float16)hi[e]; }
  return r;
}

// Device-coherent (MALL-direct) 16B load of h: two relaxed agent atomic 8B loads.
// Relaxed agent atomics lower to sc0/sc1 accesses that bypass the per-XCD L2 —
// no buffer_inv/buffer_wbl2 cache maintenance (the round-3 bottleneck).
__device__ __forceinline__ f16x8 ld_h16(const _Float16* p) {
  const unsigned long long* q = reinterpret_cast<const unsigned long long*>(p);
  unsigned long long lo = __hip_atomic_load(q,     __ATOMIC_RELAXED, __HIP_MEMORY_SCOPE_AGENT);
  unsigned long long hi = __hip_atomic_load(q + 1, __ATOMIC_RELAXED, __HIP_MEMORY_SCOPE_AGENT);
  union { unsigned long long u[2]; f16x8 v; } c;
  c.u[0] = lo; c.u[1] = hi;
  return c.v;
}

__device__ __forceinline__ void st_h8(_Float16* p, f16x4 v) {
  union { f16x4 v; unsigned long long u; } c;
  c.v = v;
  __hip_atomic_store(reinterpret_cast<unsigned long long*>(p), c.u,
                     __ATOMIC_RELAXED, __HIP_MEMORY_SCOPE_AGENT);
}

// Persistent pipeline, 128 active blocks: layer = blockIdx&7 (XCD heuristic only;
// correctness relies solely on MALL-coherent relaxed atomics). Each block: 32 cols,
// weights in VGPRs, 4 waves split k (waves 0-1 input GEMM, 2-3 hidden GEMM).
__global__ __launch_bounds__(256, 1) void rnn_persist(
    const float* __restrict__ x,   // [B][L][H] f32
    const float* __restrict__ h0,  // [NL][B][H] f32
    const float* __restrict__ WI,  // [NL][H][H] f32
    const float* __restrict__ BI,  // [NL][H]
    const float* __restrict__ WH,  // [NL][H][H] f32
    const float* __restrict__ BH,  // [NL][H]
    float* __restrict__ out,       // [B][L][H] f32 ++ hfinal [NL][B][H]
    _Float16* __restrict__ hbuf,   // [NL][RS][B][H] f16 ring
    unsigned* __restrict__ pflag) {// [NL][TPL] progress: t+1 after step t
  const int l = blockIdx.x & 7;
  if (l >= NL) return;
  const int tile = blockIdx.x >> 3;   // 0..31
  const int c0   = tile * CPB;
  const int tid  = threadIdx.x;
  const int w    = tid >> 6;          // wave 0..3
  const int lane = tid & 63;
  const int crow = lane & 15;
  const int kgrp = lane >> 4;
  const int kofs = (w & 1) * 512;     // k offset within the 1024-wide matrix

  // ---- weight fragments -> registers (once) ----
  f16x8 wfrag[2][16];
  {
    const float* Wb = (w < 2 ? WI : WH) + (size_t)l * HH * HH;
#pragma unroll
    for (int ct = 0; ct < 2; ++ct) {
      const float* wr = Wb + (size_t)(c0 + ct * 16 + crow) * HH + kofs + kgrp * 8;
#pragma unroll
      for (int j = 0; j < 16; ++j) wfrag[ct][j] = cvt8(wr + j * 32);
    }
  }

  // ---- epilogue assignment: thread -> (batch row rb, 4 cols at c4) ----
  const int rb = tid >> 3;          // 0..31
  const int c4 = (tid & 7) * 4;     // 0,4,...,28
  float bias[4];
#pragma unroll
  for (int j = 0; j < 4; ++j)
    bias[j] = BI[l * HH + c0 + c4 + j] + BH[l * HH + c0 + c4 + j];

  __shared__ float red[4][2][16][34];   // [wave][rowtile][row][col+pad]

  for (int t = 0; t < LL; ++t) {
    // ---------- wait for dependencies (relaxed MALL loads, no cache maint) ----------
    if (tid < 64) {
      const int L = tid & 31;
      if (t > 0)   // own layer finished t-1 (peers' h needed)
        while (__hip_atomic_load(&pflag[l * TPL + L], __ATOMIC_RELAXED,
                                 __HIP_MEMORY_SCOPE_AGENT) < (unsigned)t)
          __builtin_amdgcn_s_sleep(1);
      if (l > 0)   // layer l-1 finished t
        while (__hip_atomic_load(&pflag[(l - 1) * TPL + L], __ATOMIC_RELAXED,
                                 __HIP_MEMORY_SCOPE_AGENT) < (unsigned)(t + 1))
          __builtin_amdgcn_s_sleep(1);
      if (l < NL - 1 && t >= RS)  // WAR: layer l+1 consumed ring slot t-RS
        while (__hip_atomic_load(&pflag[(l + 1) * TPL + L], __ATOMIC_RELAXED,
                                 __HIP_MEMORY_SCOPE_AGENT) < (unsigned)(t - (RS - 1)))
          __builtin_amdgcn_s_sleep(1);
    }
    __syncthreads();

    // ---------- A fragments ----------
    f16x8 a[2][16];
    if (w < 2) {            // input operand
      if (l == 0) {
#pragma unroll
        for (int rt = 0; rt < 2; ++rt) {
          const float* r = x + ((size_t)(rt * 16 + crow) * LL + t) * HH + kofs + kgrp * 8;
#pragma unroll
          for (int j = 0; j < 16; ++j) a[rt][j] = cvt8(r + j * 32);
        }
      } else {
        const _Float16* hb =
            hbuf + ((size_t)((l - 1) * RS + (t & (RS - 1))) * BB) * HH + kofs + kgrp * 8;
#pragma unroll
        for (int rt = 0; rt < 2; ++rt)
#pragma unroll
          for (int j = 0; j < 16; ++j)
            a[rt][j] = ld_h16(hb + (size_t)(rt * 16 + crow) * HH + j * 32);
      }
    } else {                // hidden operand
      if (t == 0) {
#pragma unroll
        for (int rt = 0; rt < 2; ++rt) {
          const float* r = h0 + ((size_t)l * BB + rt * 16 + crow) * HH + kofs + kgrp * 8;
#pragma unroll
          for (int j = 0; j < 16; ++j) a[rt][j] = cvt8(r + j * 32);
        }
      } else {
        const _Float16* hb =
            hbuf + ((size_t)(l * RS + ((t - 1) & (RS - 1))) * BB) * HH + kofs + kgrp * 8;
#pragma unroll
        for (int rt = 0; rt < 2; ++rt)
#pragma unroll
          for (int j = 0; j < 16; ++j)
            a[rt][j] = ld_h16(hb + (size_t)(rt * 16 + crow) * HH + j * 32);
      }
    }

    // ---------- MFMA ----------
    f32x4 acc[2][2];
#pragma unroll
    for (int ct = 0; ct < 2; ++ct)
#pragma unroll
      for (int rt = 0; rt < 2; ++rt) acc[ct][rt] = (f32x4){0.f, 0.f, 0.f, 0.f};
#pragma unroll
    for (int j = 0; j < 16; ++j)
#pragma unroll
      for (int ct = 0; ct < 2; ++ct)
#pragma unroll
        for (int rt = 0; rt < 2; ++rt)
          acc[ct][rt] = __builtin_amdgcn_mfma_f32_16x16x32_f16(a[rt][j], wfrag[ct][j],
                                                               acc[ct][rt], 0, 0, 0);

    // ---------- cross-wave k-reduce via LDS ----------
#pragma unroll
    for (int ct = 0; ct < 2; ++ct)
#pragma unroll
      for (int rt = 0; rt < 2; ++rt)
#pragma unroll
        for (int r = 0; r < 4; ++r)
          red[w][rt][kgrp * 4 + r][ct * 16 + crow] = acc[ct][rt][r];
    __syncthreads();

    float v[4];
#pragma unroll
    for (int j = 0; j < 4; ++j) {
      float s = bias[j];
#pragma unroll
      for (int w2 = 0; w2 < 4; ++w2) s += red[w2][rb >> 4][rb & 15][c4 + j];
      v[j] = tanhf(s);
    }

    {  // h ring store: 8B MALL-direct store
      f16x4 hv;
#pragma unroll
      for (int j = 0; j < 4; ++j) hv[j] = (_Float16)v[j];
      st_h8(hbuf + ((size_t)(l * RS + (t & (RS - 1))) * BB + rb) * HH + c0 + c4, hv);
    }
    if (l == NL - 1) {
      f32x4 o = {v[0], v[1], v[2], v[3]};
      __builtin_nontemporal_store(
          o, reinterpret_cast<f32x4*>(out + ((size_t)rb * LL + t) * HH + c0 + c4));
    }
    if (t == LL - 1) {
      f32x4 o = {v[0], v[1], v[2], v[3]};
      __builtin_nontemporal_store(
          o, reinterpret_cast<f32x4*>(out + (size_t)BB * LL * HH +
                                      ((size_t)l * BB + rb) * HH + c0 + c4));
    }
    __syncthreads();   // s_waitcnt vmcnt(0) before barrier: h stores acked at MALL

    // ---------- publish progress (relaxed store; ordering by the drain above) ----------
    if (tid == 0)
      __hip_atomic_store(&pflag[l * TPL + tile], (unsigned)(t + 1), __ATOMIC_RELAXED,
                         __HIP_MEMORY_SCOPE_AGENT);
  }
}

extern "C" void kernel_launch(void* const* d_in, const int* in_sizes, int n_in,
                              void* d_out, int out_size, void* d_ws, size_t ws_size,
                              hipStream_t stream) {
  const float* x  = (const float*)d_in[0];
  const float* h0 = (const float*)d_in[1];
  const float* WI = (const float*)d_in[2];
  const float* BI = (const float*)d_in[3];
  const float* WH = (const float*)d_in[4];
  const float* BH = (const float*)d_in[5];
  float* out = (float*)d_out;

  const size_t hbytes = (size_t)NL * RS * BB * HH * sizeof(_Float16);  // 2 MB
  _Float16* hbuf = (_Float16*)d_ws;
  unsigned* pflag = (unsigned*)((char*)d_ws + hbytes);

  hipMemsetAsync(pflag, 0, (size_t)NL * TPL * sizeof(unsigned), stream);
  rnn_persist<<<256, 256, 0, stream>>>(x, h0, WI, BI, WH, BH, out, hbuf, pflag);
}

// Round 6
// 7930.131 us; speedup vs baseline: 1.0455x; 1.0455x over previous
//
#include <hip/hip_runtime.h>
#include <hip/hip_fp16.h>

#define BB 32
#define LL 512
#define HH 1024
#define NL 4
#define RS 8     // h ring slots per layer
#define TPL 32   // blocks (tiles) per layer
#define CPB 32   // output cols per block
#define TAGM 0x0001000100010001ULL   // LSB of each f16 in an 8B quantum

typedef _Float16 f16x8 __attribute__((ext_vector_type(8)));
typedef float    f32x4 __attribute__((ext_vector_type(4)));

__device__ __forceinline__ f16x8 cvt8(const float* __restrict__ p) {
  f32x4 lo = *reinterpret_cast<const f32x4*>(p);
  f32x4 hi = *reinterpret_cast<const f32x4*>(p + 4);
  f16x8 r;
#pragma unroll
  for (int e = 0; e < 4; ++e) { r[e] = (_Float16)lo[e]; r[e + 4] = (_Float16)hi[e]; }
  return r;
}

// Spin-load 16 MFMA fragments (32 x 8B quanta) for one row; every f16's LSB
// must equal the generation-parity tag. Tag+payload arrive in one MALL round
// trip (8B relaxed agent atomics are single-copy; no separate flag needed).
// Lanes with all-valid data exit; stragglers re-load (exec-masked) until valid.
__device__ __forceinline__ void spin_load_row16(f16x8* __restrict__ o,
                                                const _Float16* __restrict__ base,
                                                unsigned long long wantv) {
  const unsigned long long* p = reinterpret_cast<const unsigned long long*>(base);
  unsigned long long q0[16], q1[16];
#pragma unroll
  for (int j = 0; j < 16; ++j) {
    q0[j] = __hip_atomic_load(p + j * 8,     __ATOMIC_RELAXED, __HIP_MEMORY_SCOPE_AGENT);
    q1[j] = __hip_atomic_load(p + j * 8 + 1, __ATOMIC_RELAXED, __HIP_MEMORY_SCOPE_AGENT);
  }
  for (;;) {
    unsigned long long bad = 0;
#pragma unroll
    for (int j = 0; j < 16; ++j)
      bad |= ((q0[j] ^ wantv) | (q1[j] ^ wantv)) & TAGM;
    if (bad == 0) break;
#pragma unroll
    for (int j = 0; j < 16; ++j) {
      q0[j] = __hip_atomic_load(p + j * 8,     __ATOMIC_RELAXED, __HIP_MEMORY_SCOPE_AGENT);
      q1[j] = __hip_atomic_load(p + j * 8 + 1, __ATOMIC_RELAXED, __HIP_MEMORY_SCOPE_AGENT);
    }
  }
#pragma unroll
  for (int j = 0; j < 16; ++j) {
    union { unsigned long long u[2]; f16x8 v; } c;
    c.u[0] = q0[j]; c.u[1] = q1[j];
    o[j] = c.v;
  }
}

// Persistent pipeline, 128 active blocks: layer = blockIdx&7 (XCD heuristic
// only). Block: 32 cols, weights in VGPRs; waves 0-1 input GEMM, 2-3 hidden.
// Sync: h data self-validating via LSB tags; per-tile flags only for ring WAR.
__global__ __launch_bounds__(256, 1) void rnn_persist(
    const float* __restrict__ x,   // [B][L][H] f32
    const float* __restrict__ h0,  // [NL][B][H] f32
    const float* __restrict__ WI,  // [NL][H][H] f32
    const float* __restrict__ BI,  // [NL][H]
    const float* __restrict__ WH,  // [NL][H][H] f32
    const float* __restrict__ BH,  // [NL][H]
    float* __restrict__ out,       // [B][L][H] f32 ++ hfinal [NL][B][H]
    _Float16* __restrict__ hbuf,   // [NL][RS][B][H] f16 ring (tagged)
    unsigned* __restrict__ pflag) {// [NL][TPL]: t+1 after step t (WAR only)
  const int l = blockIdx.x & 7;
  if (l >= NL) return;
  const int tile = blockIdx.x >> 3;   // 0..31
  const int c0   = tile * CPB;
  const int tid  = threadIdx.x;
  const int w    = tid >> 6;          // wave 0..3
  const int lane = tid & 63;
  const int crow = lane & 15;
  const int kgrp = lane >> 4;
  const int kofs = (w & 1) * 512;     // k offset within the 1024-wide matrix

  // ---- weight fragments -> registers (once) ----
  f16x8 wfrag[2][16];
  {
    const float* Wb = (w < 2 ? WI : WH) + (size_t)l * HH * HH;
#pragma unroll
    for (int ct = 0; ct < 2; ++ct) {
      const float* wr = Wb + (size_t)(c0 + ct * 16 + crow) * HH + kofs + kgrp * 8;
#pragma unroll
      for (int j = 0; j < 16; ++j) wfrag[ct][j] = cvt8(wr + j * 32);
    }
  }

  // ---- epilogue assignment: thread -> (batch row rb, 4 cols at c4) ----
  const int rb = tid >> 3;          // 0..31
  const int c4 = (tid & 7) * 4;     // 0,4,...,28
  float bias[4];
#pragma unroll
  for (int j = 0; j < 4; ++j)
    bias[j] = BI[l * HH + c0 + c4 + j] + BH[l * HH + c0 + c4 + j];

  __shared__ float red[2][4][2][16][34];   // [pingpong][wave][rowtile][row][col+pad]

  for (int t = 0; t < LL; ++t) {
    // ---------- WAR gate (7-step slack; off critical path). Gates the h-ring
    // stores below via the reduce barrier (pollers must arrive there). ----------
    if (t >= RS && tid < 64) {
      const int Lt = tid & 31;
      if (tid < 32) {        // own-layer peers done reading gen t-8 (their step t-7)
        while (__hip_atomic_load(&pflag[l * TPL + Lt], __ATOMIC_RELAXED,
                                 __HIP_MEMORY_SCOPE_AGENT) < (unsigned)(t - 6))
          __builtin_amdgcn_s_sleep(1);
      } else if (l < NL - 1) {  // layer l+1 done reading gen t-8 (its step t-8)
        while (__hip_atomic_load(&pflag[(l + 1) * TPL + Lt], __ATOMIC_RELAXED,
                                 __HIP_MEMORY_SCOPE_AGENT) < (unsigned)(t - 7))
          __builtin_amdgcn_s_sleep(1);
      }
    }

    // ---------- phased operand load + MFMA (caps VGPR pressure) ----------
    const unsigned long long wantWI = ((t >> 3) & 1) ? TAGM : 0ULL;
    const unsigned long long wantWH = (((t - 1) >> 3) & 1) ? TAGM : 0ULL;

    f32x4 acc[2][2];
#pragma unroll
    for (int ct = 0; ct < 2; ++ct)
#pragma unroll
      for (int rt = 0; rt < 2; ++rt) acc[ct][rt] = (f32x4){0.f, 0.f, 0.f, 0.f};

#pragma unroll
    for (int rt = 0; rt < 2; ++rt) {
      f16x8 af[16];
      if (w < 2) {            // input operand: x (l==0) or layer l-1 h^t
        if (l == 0) {
          const float* r = x + ((size_t)(rt * 16 + crow) * LL + t) * HH + kofs + kgrp * 8;
#pragma unroll
          for (int j = 0; j < 16; ++j) af[j] = cvt8(r + j * 32);
        } else {
          const _Float16* hb =
              hbuf + ((size_t)((l - 1) * RS + (t & (RS - 1))) * BB) * HH + kofs + kgrp * 8;
          spin_load_row16(af, hb + (size_t)(rt * 16 + crow) * HH, wantWI);
        }
      } else {                // hidden operand: h0 (t==0) or own h^{t-1}
        if (t == 0) {
          const float* r = h0 + ((size_t)l * BB + rt * 16 + crow) * HH + kofs + kgrp * 8;
#pragma unroll
          for (int j = 0; j < 16; ++j) af[j] = cvt8(r + j * 32);
        } else {
          const _Float16* hb =
              hbuf + ((size_t)(l * RS + ((t - 1) & (RS - 1))) * BB) * HH + kofs + kgrp * 8;
          spin_load_row16(af, hb + (size_t)(rt * 16 + crow) * HH, wantWH);
        }
      }
#pragma unroll
      for (int j = 0; j < 16; ++j)
#pragma unroll
        for (int ct = 0; ct < 2; ++ct)
          acc[ct][rt] = __builtin_amdgcn_mfma_f32_16x16x32_f16(af[j], wfrag[ct][j],
                                                               acc[ct][rt], 0, 0, 0);
    }

    // ---------- cross-wave k-reduce via LDS (ping-pong, ONE barrier/step) ----------
    const int pp = t & 1;
#pragma unroll
    for (int ct = 0; ct < 2; ++ct)
#pragma unroll
      for (int rt = 0; rt < 2; ++rt)
#pragma unroll
        for (int r = 0; r < 4; ++r)
          red[pp][w][rt][kgrp * 4 + r][ct * 16 + crow] = acc[ct][rt][r];
    __syncthreads();

    float v[4];
#pragma unroll
    for (int j = 0; j < 4; ++j) {
      float s = bias[j];
#pragma unroll
      for (int w2 = 0; w2 < 4; ++w2) s += red[pp][w2][rb >> 4][rb & 15][c4 + j];
      v[j] = tanhf(s);
    }

    // ---------- h ring store: pack 4xf16, force LSB tag, one 8B atomic ----------
    {
      union { _Float16 h[4]; unsigned long long u; } pk;
#pragma unroll
      for (int j = 0; j < 4; ++j) pk.h[j] = (_Float16)v[j];
      pk.u = (pk.u & ~TAGM) | (((t >> 3) & 1) ? TAGM : 0ULL);
      __hip_atomic_store(
          reinterpret_cast<unsigned long long*>(
              hbuf + ((size_t)(l * RS + (t & (RS - 1))) * BB + rb) * HH + c0 + c4),
          pk.u, __ATOMIC_RELAXED, __HIP_MEMORY_SCOPE_AGENT);
    }

    // ---------- WAR progress flag (reads for step t all complete: data consumed) ----------
    if (tid == 0)
      __hip_atomic_store(&pflag[l * TPL + tile], (unsigned)(t + 1), __ATOMIC_RELAXED,
                         __HIP_MEMORY_SCOPE_AGENT);

    // ---------- out stores (fire-and-forget, off critical path) ----------
    if (l == NL - 1) {
      f32x4 o = {v[0], v[1], v[2], v[3]};
      __builtin_nontemporal_store(
          o, reinterpret_cast<f32x4*>(out + ((size_t)rb * LL + t) * HH + c0 + c4));
    }
    if (t == LL - 1) {
      f32x4 o = {v[0], v[1], v[2], v[3]};
      __builtin_nontemporal_store(
          o, reinterpret_cast<f32x4*>(out + (size_t)BB * LL * HH +
                                      ((size_t)l * BB + rb) * HH + c0 + c4));
    }
  }
}

extern "C" void kernel_launch(void* const* d_in, const int* in_sizes, int n_in,
                              void* d_out, int out_size, void* d_ws, size_t ws_size,
                              hipStream_t stream) {
  const float* x  = (const float*)d_in[0];
  const float* h0 = (const float*)d_in[1];
  const float* WI = (const float*)d_in[2];
  const float* BI = (const float*)d_in[3];
  const float* WH = (const float*)d_in[4];
  const float* BH = (const float*)d_in[5];
  float* out = (float*)d_out;

  const size_t hbytes = (size_t)NL * RS * BB * HH * sizeof(_Float16);  // 2 MB
  _Float16* hbuf = (_Float16*)d_ws;
  unsigned* pflag = (unsigned*)((char*)d_ws + hbytes);

  // 0xFF: every f16 LSB=1 -> invalid for generation-0 (parity 0) consumers.
  hipMemsetAsync(hbuf, 0xFF, hbytes, stream);
  hipMemsetAsync(pflag, 0, (size_t)NL * TPL * sizeof(unsigned), stream);
  rnn_persist<<<256, 256, 0, stream>>>(x, h0, WI, BI, WH, BH, out, hbuf, pflag);
}